// Round 6
// baseline (1148.400 us; speedup 1.0000x reference)
//
#include <hip/hip_runtime.h>
#include <math.h>

// ---- ws layout (float-slot offsets) ----
#define WS_CB     0         // 192
#define WS_QE1    192       // 16384
#define WS_XE1    16576     // 65536
#define WS_G      82112     // 65536
#define WS_HW     147648    // 266240
#define WS_U16    413888    // 8192 u32
#define WS_WHH16  422080    // 6144 u32
#define WS_W2M16  428224    // 6144 u32
#define WS_GFLAG  442560    // 256 u32

typedef _Float16 h2 __attribute__((ext_vector_type(2)));

#if defined(__has_builtin)
#if __has_builtin(__builtin_amdgcn_fdot2)
#define FDOT2(a,b,c) __builtin_amdgcn_fdot2((a),(b),(c),false)
#endif
#endif
#ifndef FDOT2
__device__ inline float fdot2_sw(h2 a, h2 b, float c){ return c + (float)a[0]*(float)b[0] + (float)a[1]*(float)b[1]; }
#define FDOT2(a,b,c) fdot2_sw((a),(b),(c))
#endif

__device__ inline h2 H2(unsigned u){ union{unsigned x; h2 h;} v; v.x=u; return v.h; }
__device__ inline unsigned short F2H(float f){ union{_Float16 h; unsigned short s;} v; v.h=(_Float16)f; return v.s; }
__device__ inline unsigned PACK2(float a, float b){ return (unsigned)F2H(a) | ((unsigned)F2H(b)<<16); }

// plain volatile LDS flag poll
#define POLLGE(F,T) do{ while(*(volatile int*)&(F) < (T)) {} asm volatile("" ::: "memory"); }while(0)

// ---- dynamic-LDS word offsets (u32 units) ----
// weight tables: 10 units x 2048 words (each: [d4 0..7][g 0..63][4 sub] u32)
//   unit 0..3 : U (m1, pr, pz, pn)    unit 4: w2n   unit 5: m2r  unit 6: m2z
//   unit 7: wr  unit 8: wz  unit 9: wn
#define LW_WT    0
#define LW_H16   20480   // [4][16][32] u32  (f16 rows, 64 halves)
#define LW_A16   22528   // [4][8][32] u32
#define LW_INB   23552   // [16][32] u32
#define LW_GI4   24064   // [4][8][64] float4 (8192 u32)
#define LW_H32   32256   // [4][8][64] f32 (2048 u32)
#define LW_FLG   34304   // flags: [0..3]=flgH, [4..7]=p2s, [8..11]=ioPr
#define LDS_WORDS 34320
#define LDS_BYTES (LDS_WORDS*4)

// one 64-wide dot from LDS weight unit UIDX against row regs qq0..qq7
#define DQB(Q,D4) { uint4 _w=_wp[(D4)*64+lane]; \
  _a=FDOT2(H2(_w.x),H2(Q.x),_a); _a=FDOT2(H2(_w.y),H2(Q.y),_a); \
  _a=FDOT2(H2(_w.z),H2(Q.z),_a); _a=FDOT2(H2(_w.w),H2(Q.w),_a); }
#define DOTL(ACC,UIDX) { const uint4* _wp=(const uint4*)(ldsbuf+(UIDX)*2048); float _a=(ACC); \
  DQB(qq0,0) DQB(qq1,1) DQB(qq2,2) DQB(qq3,3) DQB(qq4,4) DQB(qq5,5) DQB(qq6,6) DQB(qq7,7) (ACC)=_a; }

#define LOADROW(P) { const uint4* _rp=(const uint4*)(P); qq0=_rp[0];qq1=_rp[1];qq2=_rp[2];qq3=_rp[3];qq4=_rp[4];qq5=_rp[5];qq6=_rp[6];qq7=_rp[7]; }

// ================= precompute =================
__global__ __launch_bounds__(256) void kPrep(
    const int* __restrict__ q, const int* __restrict__ r,
    const float* __restrict__ x_emb, const float* __restrict__ q_emb,
    const float* __restrict__ init_h, const float* __restrict__ w1,
    const float* __restrict__ b1, const float* __restrict__ w2,
    const float* __restrict__ b2, const float* __restrict__ w_ih,
    const float* __restrict__ w_hh, const float* __restrict__ b_ih,
    float* __restrict__ ws, float* __restrict__ h_full)
{
  int idx = blockIdx.x*256 + threadIdx.x;
  unsigned* wsu = (unsigned*)ws;
  if (idx < 192) {
    int g = idx; float s = b_ih[g];
    for (int j=0;j<64;j++) s += b2[j]*w_ih[g*128+j];
    ws[WS_CB+g] = s;
  } else if (idx < 16576) {
    int e = idx-192; int c = e>>6, i = e&63;
    float s = b1[i];
    for (int k=0;k<64;k++) s += q_emb[c*64+k]*w1[(64+k)*64+i];
    ws[WS_QE1+e] = s;
  } else if (idx < 82112) {
    int e = idx-16576; int bt = e>>6, i = e&63;
    int row = q[bt] + 256*r[bt];
    float s = b1[i];
    for (int k=0;k<64;k++) s += x_emb[row*64+k]*w1[(64+k)*64+i];
    ws[WS_XE1+e] = s;
  } else if (idx < 147648) {
    int e = idx-82112; int a = e>>8, cc = e&255;
    float s = 0.f;
    for (int d=0;d<64;d++) s += q_emb[a*64+d]*q_emb[cc*64+d];
    ws[WS_G+e] = s;
  } else if (idx < 409792) {
    int e = idx-147648; int bb = e>>14, cf = e&16383;
    h_full[(size_t)bb*65*16384 + cf] = init_h[cf];
  } else if (idx < 417984) {
    int e = idx-409792; int rr = e>>5, d = e&31;
    float v0, v1;
    if (rr < 64) { v0 = w1[(2*d)*64+rr];   v1 = w1[(2*d+1)*64+rr]; }
    else { int g = rr-64; v0 = w_ih[g*128+64+2*d]; v1 = w_ih[g*128+64+2*d+1]; }
    wsu[WS_U16+e] = PACK2(v0,v1);
  } else if (idx < 424128) {
    int e = idx-417984; int g = e>>5, d = e&31;
    wsu[WS_WHH16+e] = PACK2(w_hh[g*64+2*d], w_hh[g*64+2*d+1]);
  } else if (idx < 430272) {
    int e = idx-424128; int g = e>>5, d = e&31;
    float s0=0.f, s1=0.f;
    for (int j=0;j<64;j++){ float wij = w_ih[g*128+j]; s0 += w2[(2*d)*64+j]*wij; s1 += w2[(2*d+1)*64+j]*wij; }
    wsu[WS_W2M16+e] = PACK2(s0,s1);
  }
}

// ================= wavefront recurrence v6: weights in LDS =================
// 256 WGs x 512 threads, 1 WG/CU. b=bid&15, tg=bid>>4, chains t=4*tg+i.
// waves 0-3: crit (gh + a.W2m_{r,z} + gates). waves 4-7: helper (U-dots + g2n + I/O).
// All weight matrices staged once into dynamic LDS ([d/4][g][4] interleave,
// lane-stride-1 ds_read_b128, conflict-free). VGPR stays low -> no remat/spill.
__global__ __launch_bounds__(512) void kA(
    const int* __restrict__ q, const float* __restrict__ b_hh,
    float* __restrict__ ws, float* __restrict__ h_full)
{
  extern __shared__ unsigned ldsbuf[];

  const int bid=blockIdx.x, b=bid&15, tg=bid>>4;
  const int tid=threadIdx.x, w=tid>>6, lane=tid&63;
  const bool isA = (w<4);
  const int i = isA? w : w-4;
  const int t = tg*4 + i;

  const unsigned* U16  = (const unsigned*)ws + WS_U16;
  const unsigned* WH16 = (const unsigned*)ws + WS_WHH16;
  const unsigned* WM16 = (const unsigned*)ws + WS_W2M16;
  const float* qe1 = ws + WS_QE1;
  const float* xe1 = ws + WS_XE1;
  const float* cb  = ws + WS_CB;
  unsigned* gflag = (unsigned*)ws + WS_GFLAG;

  // ring/flag pointers into dynamic LDS
  unsigned short* h16s = (unsigned short*)(ldsbuf + LW_H16);   // [4][16][64] halves
  unsigned short* a16s = (unsigned short*)(ldsbuf + LW_A16);   // [4][8][64]
  unsigned short* inbox= (unsigned short*)(ldsbuf + LW_INB);   // [16][64]
  float4* gi4s = (float4*)(ldsbuf + LW_GI4);                   // [4][8][64]
  float*  h32s = (float*)(ldsbuf + LW_H32);                    // [4][8][64]
  int* FLG = (int*)(ldsbuf + LW_FLG);
  int* flgH = FLG; int* p2s = FLG+4; int* ioPr = FLG+8;

  // ---- stage weights global -> LDS (transposed-interleaved) ----
  for (int idx = tid; idx < 20480; idx += 512) {
    int unit = idx>>11, ww = idx&2047;
    int d4 = (ww>>8)&7, g = (ww>>2)&63, sub = ww&3;
    int d = d4*4+sub;
    unsigned v;
    if (unit < 4)      v = U16 [(unit*64+g)*32 + d];
    else if (unit==4)  v = WM16[(128+g)*32 + d];
    else if (unit==5)  v = WM16[(g)*32 + d];
    else if (unit==6)  v = WM16[(64+g)*32 + d];
    else if (unit==7)  v = WH16[(g)*32 + d];
    else if (unit==8)  v = WH16[(64+g)*32 + d];
    else               v = WH16[(128+g)*32 + d];
    ldsbuf[idx] = v;
  }
  if (tid<12) FLG[tid]=0;
  if (isA) h16s[(i*16+15)*64 + lane] = 0;   // h(-1)=0
  __syncthreads();

  uint4 qq0,qq1,qq2,qq3,qq4,qq5,qq6,qq7;

  if (isA) {
    // ---- crit wave ----
    const float bhr=b_hh[lane], bhz=b_hh[64+lane], bhn=b_hh[128+lane];
    float hreg=0.f;
    for (int c=0;c<256;c++){
      if (((c&7)==0) && i<3) POLLGE(p2s[i+1], c-8);   // h16 ring reuse by next chain's helper
      if ((c&3)==0) POLLGE(ioPr[i], c-4);             // h32 ring reuse (copyout progress)
      LOADROW(&h16s[(i*16+((c+15)&15))*64])           // own row c-1
      float ghr=bhr, ghz=bhz, ghn=bhn;
      DOTL(ghr,7) DOTL(ghz,8) DOTL(ghn,9)
      if ((c&1)==0) { int tg2=c+2; if (tg2>256) tg2=256; POLLGE(p2s[i], tg2); }  // gi/a16 ready (batched x2)
      float4 gv = gi4s[(i*8+(c&7))*64 + lane];
      LOADROW(&a16s[(i*8+(c&7))*64])
      float g2r=0.f, g2z=0.f;
      DOTL(g2r,5) DOTL(g2z,6)
      float rg = 1.f/(1.f+__expf(-(gv.x+g2r+ghr)));
      float zg = 1.f/(1.f+__expf(-(gv.y+g2z+ghz)));
      float xn = gv.z + rg*ghn;
      float e2 = __expf(2.f*xn);
      float ng = 1.f-2.f/(e2+1.f);
      hreg = zg*hreg + (1.f-zg)*ng;
      h16s[(i*16+(c&15))*64 + lane]=F2H(hreg);
      h32s[(i*8+(c&7))*64 + lane]=hreg;
      asm volatile("s_waitcnt lgkmcnt(0)" ::: "memory");
      if (lane==0) *(volatile int*)&flgH[i]=c+1;
    }
  } else {
    // ---- helper wave ----
    const float cbr=cb[lane], cbz=cb[64+lane], cbn=cb[128+lane];
    const int qrow=q[b*64+t];
    const float xr=xe1[(b*64+t)*64+lane];
    const float* hfp = h_full + (size_t)(b*65+4*tg)*16384;
    float* hfoF = h_full + (size_t)(b*65+t+1)*16384;
    unsigned* hfoU = (unsigned*)hfoF;
    unsigned* gfp = gflag + (b*16+tg-1);
    unsigned* gfc = gflag + (b*16+tg);
    const bool pubG = (i==3) && (tg<15);
    unsigned gv=0; int pfrow=0, cp=0;
    float e1cur = (qrow==0)? xr : qe1[lane];
    float prP=0.f,pzP=0.f,pnP=0.f;

    for (int s=0;s<=256;s++){
      if ((s&3)==0) POLLGE(flgH[i], s-4);   // a16/gi ring reuse (depth 8)
      float e1n=0.f;
      if (s<255) e1n = ((s+1)==qrow)? xr : qe1[(s+1)*64+lane];
      float pr=0.f,pz=0.f,pn=0.f;
      if (s<=255){
        if (i==0){
          // blocking fill to row s, opportunistic 1 ahead (depth<=8)
          while (pfrow<=s){
            if (tg>0){
              while (gv < (unsigned)(pfrow+1)){
                gv = __hip_atomic_load(gfp,__ATOMIC_RELAXED,__HIP_MEMORY_SCOPE_AGENT);
                if (gv < (unsigned)(pfrow+1)) __builtin_amdgcn_s_sleep(1);
              }
              union{unsigned u; float f;} cv;
              cv.u = __hip_atomic_load((const unsigned*)&hfp[pfrow*64+lane],__ATOMIC_RELAXED,__HIP_MEMORY_SCOPE_AGENT);
              inbox[(pfrow&15)*64+lane]=F2H(cv.f);
            } else {
              inbox[(pfrow&15)*64+lane]=F2H(hfp[pfrow*64+lane]);
            }
            pfrow++;
          }
          if (pfrow<=s+8){
            bool can=(tg==0);
            if (tg>0){
              if (gv>=(unsigned)(pfrow+1)) can=true;
              else if ((s&1)==0){ gv=__hip_atomic_load(gfp,__ATOMIC_RELAXED,__HIP_MEMORY_SCOPE_AGENT); can = gv>=(unsigned)(pfrow+1); }
            }
            if (can){
              if (tg>0){
                union{unsigned u; float f;} cv;
                cv.u = __hip_atomic_load((const unsigned*)&hfp[pfrow*64+lane],__ATOMIC_RELAXED,__HIP_MEMORY_SCOPE_AGENT);
                inbox[(pfrow&15)*64+lane]=F2H(cv.f);
              } else {
                inbox[(pfrow&15)*64+lane]=F2H(hfp[pfrow*64+lane]);
              }
              pfrow++;
            }
          }
        } else {
          POLLGE(flgH[i-1], s+1);
        }
        LOADROW( (i==0)? &inbox[(s&15)*64] : &h16s[((i-1)*16+(s&15))*64] )
        float m1=e1cur; pr=cbr; pz=cbz; pn=cbn;
        DOTL(m1,0) DOTL(pr,1) DOTL(pz,2) DOTL(pn,3)
        a16s[(i*8+(s&7))*64+lane]=F2H(fmaxf(m1,0.f));
      }
      if (s>=1){
        LOADROW(&a16s[(i*8+((s-1)&7))*64])
        float g2n=0.f; DOTL(g2n,4)
        gi4s[(i*8+((s-1)&7))*64+lane]=make_float4(prP,pzP,pnP+g2n,0.f);
      }
      asm volatile("s_waitcnt lgkmcnt(0)" ::: "memory");
      if (lane==0) *(volatile int*)&p2s[i]=s;
      prP=pr; pzP=pz; pnP=pn; e1cur=e1n;
      // opportunistic copyout (<=2 rows/step)
      int av=*(volatile int*)&flgH[i];
      asm volatile("" ::: "memory");
      int nc=0;
      while (cp<av && nc<2){
        float hv=h32s[(i*8+(cp&7))*64+lane];
        if (i==3){ union{float f; unsigned u;} cu; cu.f=hv;
          __hip_atomic_store(&hfoU[cp*64+lane],cu.u,__ATOMIC_RELAXED,__HIP_MEMORY_SCOPE_AGENT);
        } else hfoF[cp*64+lane]=hv;
        cp++; nc++;
        if ((cp&3)==0){
          *(volatile int*)&ioPr[i]=cp;
          if (pubG){ asm volatile("s_waitcnt vmcnt(0)" ::: "memory");
            if (lane==0) __hip_atomic_store(gfc,(unsigned)cp,__ATOMIC_RELAXED,__HIP_MEMORY_SCOPE_AGENT); }
        }
      }
    }
    // drain remaining rows
    while (cp<256){
      POLLGE(flgH[i], cp+1);
      float hv=h32s[(i*8+(cp&7))*64+lane];
      if (i==3){ union{float f; unsigned u;} cu; cu.f=hv;
        __hip_atomic_store(&hfoU[cp*64+lane],cu.u,__ATOMIC_RELAXED,__HIP_MEMORY_SCOPE_AGENT);
      } else hfoF[cp*64+lane]=hv;
      cp++;
      if ((cp&3)==0){
        *(volatile int*)&ioPr[i]=cp;
        if (pubG){ asm volatile("s_waitcnt vmcnt(0)" ::: "memory");
          if (lane==0) __hip_atomic_store(gfc,(unsigned)cp,__ATOMIC_RELAXED,__HIP_MEMORY_SCOPE_AGENT); }
      }
    }
  }
}

// ================= hw[b][u][c] = h_full[b][u][c][:] . out_w =================
__global__ __launch_bounds__(256) void kHw(const float* __restrict__ h_full,
    const float* __restrict__ out_w, float* __restrict__ hw)
{
  __shared__ float ow[64];
  if (threadIdx.x < 64) ow[threadIdx.x] = out_w[threadIdx.x];
  __syncthreads();
  const int blk = blockIdx.x, c = threadIdx.x;
  const float* hp = h_full + ((size_t)blk*256 + c)*64;
  float s = 0.f;
  #pragma unroll
  for (int f=0; f<64; f++) s += hp[f]*ow[f];
  hw[blk*256+c] = s;
}

// ================= readout =================
__global__ __launch_bounds__(256) void kY(const int* __restrict__ q,
    const float* __restrict__ ws, const float* __restrict__ bias,
    const float* __restrict__ theta, float* __restrict__ y)
{
  const float* G  = ws + WS_G;
  const float* hw = ws + WS_HW;
  const int b = blockIdx.x >> 2, tq = blockIdx.x & 3;
  const int c = threadIdx.x;
  __shared__ float siml[64][256];
  for (int u=0; u<64; u++) {
    int qq = q[b*64+u];
    siml[u][c] = G[qq*256+c];
  }
  __syncthreads();
  const float rate = __expf(theta[0]);
  const float bv = bias[c];
  const float* hwb = hw + b*65*256;
  for (int tt=0; tt<16; tt++) {
    const int t = tq*16+tt;
    float mx = -1e30f;
    for (int u=0; u<=t; u++) {
      float s = __expf(-rate*(float)(t-u))*siml[u][c];
      mx = fmaxf(mx, s);
    }
    float se = 0.f, sw = 0.f;
    for (int u=0; u<=t; u++) {
      float s = __expf(-rate*(float)(t-u))*siml[u][c];
      float e = __expf(s-mx);
      se += e; sw += e*hwb[u*256+c];
    }
    float lg = hwb[(t+1)*256+c] + sw/se + bv;
    y[(b*64+t)*256+c] = 1.f/(1.f+__expf(-lg));
  }
}

extern "C" void kernel_launch(void* const* d_in, const int* in_sizes, int n_in,
                              void* d_out, int out_size, void* d_ws, size_t ws_size,
                              hipStream_t stream)
{
  (void)in_sizes; (void)n_in; (void)out_size; (void)ws_size;
  const int*   q      = (const int*)  d_in[0];
  const int*   r      = (const int*)  d_in[1];
  const float* x_emb  = (const float*)d_in[2];
  const float* q_emb  = (const float*)d_in[3];
  const float* init_h = (const float*)d_in[4];
  const float* w1     = (const float*)d_in[5];
  const float* b1     = (const float*)d_in[6];
  const float* w2     = (const float*)d_in[7];
  const float* b2     = (const float*)d_in[8];
  const float* w_ih   = (const float*)d_in[9];
  const float* w_hh   = (const float*)d_in[10];
  const float* b_ih   = (const float*)d_in[11];
  const float* b_hh   = (const float*)d_in[12];
  const float* bias   = (const float*)d_in[13];
  const float* out_w  = (const float*)d_in[14];
  const float* theta  = (const float*)d_in[15];

  float* out    = (float*)d_out;
  float* y      = out;
  float* h_full = out + 262144;
  float* ws     = (float*)d_ws;

  hipMemsetAsync((unsigned*)ws + WS_GFLAG, 0, 256*sizeof(unsigned), stream);
  kPrep<<<1681,256,0,stream>>>(q,r,x_emb,q_emb,init_h,w1,b1,w2,b2,w_ih,w_hh,b_ih,ws,h_full);
  {
    // allow >64KB dynamic LDS (160KB/CU on gfx950); attribute set is not a stream op
    static int attr_done = 0;
    (void)attr_done;
    hipFuncSetAttribute((const void*)kA, hipFuncAttributeMaxDynamicSharedMemorySize, LDS_BYTES);
    void* ka[] = { (void*)&q, (void*)&b_hh, (void*)&ws, (void*)&h_full };
    hipError_t e = hipLaunchCooperativeKernel((const void*)kA, dim3(256), dim3(512), ka, LDS_BYTES, stream);
    if (e != hipSuccess) {
      kA<<<dim3(256),dim3(512),LDS_BYTES,stream>>>(q,b_hh,ws,h_full);
    }
  }
  kHw<<<1040,256,0,stream>>>(h_full, out_w, ws + WS_HW);
  kY<<<64,256,0,stream>>>(q, ws, bias, theta, y);
}

// Round 8
// 1048.208 us; speedup vs baseline: 1.0956x; 1.0956x over previous
//
#include <hip/hip_runtime.h>
#include <math.h>

// ---- ws layout (float-slot offsets) ----
#define WS_CB     0         // 192
#define WS_QE1    192       // 16384
#define WS_XE1    16576     // 65536
#define WS_G      82112     // 65536
#define WS_HW     147648    // 266240
#define WS_U16    413888    // 8192 u32
#define WS_WHH16  422080    // 6144 u32
#define WS_W2M16  428224    // 6144 u32
#define WS_GFLAG  442560    // 256 u32

typedef _Float16 h2 __attribute__((ext_vector_type(2)));

#if defined(__has_builtin)
#if __has_builtin(__builtin_amdgcn_fdot2)
#define FDOT2(a,b,c) __builtin_amdgcn_fdot2((a),(b),(c),false)
#endif
#endif
#ifndef FDOT2
__device__ inline float fdot2_sw(h2 a, h2 b, float c){ return c + (float)a[0]*(float)b[0] + (float)a[1]*(float)b[1]; }
#define FDOT2(a,b,c) fdot2_sw((a),(b),(c))
#endif

__device__ inline h2 H2(unsigned u){ union{unsigned x; h2 h;} v; v.x=u; return v.h; }
__device__ inline unsigned short F2H(float f){ union{_Float16 h; unsigned short s;} v; v.h=(_Float16)f; return v.s; }
__device__ inline unsigned PACK2(float a, float b){ return (unsigned)F2H(a) | ((unsigned)F2H(b)<<16); }
__device__ inline float SIG(float x){ return 1.f/(1.f+__expf(-x)); }

#define POLLGE(F,T) do{ while(*(volatile int*)&(F) < (T)) {} asm volatile("" ::: "memory"); }while(0)

// read 32 halves (one K-half of a 64-wide row) into qq0..qq3 (broadcast, conflict-free)
#define LOADHALF(P) { const uint4* _rp=(const uint4*)(P); qq0=_rp[0];qq1=_rp[1];qq2=_rp[2];qq3=_rp[3]; }
// 16x fdot2 of weight array W[16] against qq0..qq3
#define DOT16(ACC,W) { float _a=(ACC); \
  _a=FDOT2(W[0],H2(qq0.x),_a); _a=FDOT2(W[1],H2(qq0.y),_a); _a=FDOT2(W[2],H2(qq0.z),_a); _a=FDOT2(W[3],H2(qq0.w),_a); \
  _a=FDOT2(W[4],H2(qq1.x),_a); _a=FDOT2(W[5],H2(qq1.y),_a); _a=FDOT2(W[6],H2(qq1.z),_a); _a=FDOT2(W[7],H2(qq1.w),_a); \
  _a=FDOT2(W[8],H2(qq2.x),_a); _a=FDOT2(W[9],H2(qq2.y),_a); _a=FDOT2(W[10],H2(qq2.z),_a); _a=FDOT2(W[11],H2(qq2.w),_a); \
  _a=FDOT2(W[12],H2(qq3.x),_a); _a=FDOT2(W[13],H2(qq3.y),_a); _a=FDOT2(W[14],H2(qq3.z),_a); _a=FDOT2(W[15],H2(qq3.w),_a); \
  (ACC)=_a; }

// ================= precompute (unchanged) =================
__global__ __launch_bounds__(256) void kPrep(
    const int* __restrict__ q, const int* __restrict__ r,
    const float* __restrict__ x_emb, const float* __restrict__ q_emb,
    const float* __restrict__ init_h, const float* __restrict__ w1,
    const float* __restrict__ b1, const float* __restrict__ w2,
    const float* __restrict__ b2, const float* __restrict__ w_ih,
    const float* __restrict__ w_hh, const float* __restrict__ b_ih,
    float* __restrict__ ws, float* __restrict__ h_full)
{
  int idx = blockIdx.x*256 + threadIdx.x;
  unsigned* wsu = (unsigned*)ws;
  if (idx < 192) {
    int g = idx; float s = b_ih[g];
    for (int j=0;j<64;j++) s += b2[j]*w_ih[g*128+j];
    ws[WS_CB+g] = s;
  } else if (idx < 16576) {
    int e = idx-192; int c = e>>6, i = e&63;
    float s = b1[i];
    for (int k=0;k<64;k++) s += q_emb[c*64+k]*w1[(64+k)*64+i];
    ws[WS_QE1+e] = s;
  } else if (idx < 82112) {
    int e = idx-16576; int bt = e>>6, i = e&63;
    int row = q[bt] + 256*r[bt];
    float s = b1[i];
    for (int k=0;k<64;k++) s += x_emb[row*64+k]*w1[(64+k)*64+i];
    ws[WS_XE1+e] = s;
  } else if (idx < 147648) {
    int e = idx-82112; int a = e>>8, cc = e&255;
    float s = 0.f;
    for (int d=0;d<64;d++) s += q_emb[a*64+d]*q_emb[cc*64+d];
    ws[WS_G+e] = s;
  } else if (idx < 409792) {
    int e = idx-147648; int bb = e>>14, cf = e&16383;
    h_full[(size_t)bb*65*16384 + cf] = init_h[cf];
  } else if (idx < 417984) {
    int e = idx-409792; int rr = e>>5, d = e&31;
    float v0, v1;
    if (rr < 64) { v0 = w1[(2*d)*64+rr];   v1 = w1[(2*d+1)*64+rr]; }
    else { int g = rr-64; v0 = w_ih[g*128+64+2*d]; v1 = w_ih[g*128+64+2*d+1]; }
    wsu[WS_U16+e] = PACK2(v0,v1);
  } else if (idx < 424128) {
    int e = idx-417984; int g = e>>5, d = e&31;
    wsu[WS_WHH16+e] = PACK2(w_hh[g*64+2*d], w_hh[g*64+2*d+1]);
  } else if (idx < 430272) {
    int e = idx-424128; int g = e>>5, d = e&31;
    float s0=0.f, s1=0.f;
    for (int j=0;j<64;j++){ float wij = w_ih[g*128+j]; s0 += w2[(2*d)*64+j]*wij; s1 += w2[(2*d+1)*64+j]*wij; }
    wsu[WS_W2M16+e] = PACK2(s0,s1);
  }
}

// ================= wavefront recurrence v8: K-split + race-fixed rings =================
// 256 WGs x 1024 threads (16 waves), 1 WG/CU. b=bid&15, tg=bid>>4, chains t=4*tg+i (i=w&3).
// role = w>>2: 0=CA(crit-low) 1=CB(crit-high) 2=HA(helper-low,combiner) 3=HB(helper-high,I/O).
// Each wave holds HALF of each weight matrix (80 h2 regs) -> fits 128-VGPR cap.
// v8 fix: HA ring-reuse polls are per-iteration (gi4 depth 4 needs flgH>=s-4;
// a16 depth 8 needs flgCB>=s-7); CA's h16-reuse polls every 4 (margin 4).
__global__ __launch_bounds__(1024) void kA(
    const int* __restrict__ q, const float* __restrict__ b_hh,
    float* __restrict__ ws, float* __restrict__ h_full)
{
  __shared__ __align__(16) unsigned short h16s[4][16][64];  // CA writes
  __shared__ __align__(16) unsigned short a16s[4][8][64];   // HA writes
  __shared__ __align__(16) unsigned short inbox[16][64];    // HB0 fills
  __shared__ __align__(16) float4 gi4s[4][4][64];           // HA writes (depth 4)
  __shared__ float h32s[4][8][64];                          // CA writes
  __shared__ float cb2ca[4][2][5][64];                      // CB partials
  __shared__ float hb2ha[4][2][5][64];                      // HB partials
  __shared__ int flgH[4], flgA[4], flgCB[4], flgHB[4], ioPr[4], inbF;

  const int bid=blockIdx.x, b=bid&15, tg=bid>>4;
  const int tid=threadIdx.x, w=tid>>6, lane=tid&63;
  const int i = w&3, role = w>>2;
  const int t = tg*4 + i;

  const unsigned* U16  = (const unsigned*)ws + WS_U16;
  const unsigned* WH16 = (const unsigned*)ws + WS_WHH16;
  const unsigned* WM16 = (const unsigned*)ws + WS_W2M16;
  const float* qe1 = ws + WS_QE1;
  const float* xe1 = ws + WS_XE1;
  const float* cb  = ws + WS_CB;
  unsigned* gflag = (unsigned*)ws + WS_GFLAG;

  if (tid<4){ flgH[tid]=0; flgA[tid]=0; flgCB[tid]=0; flgHB[tid]=0; ioPr[tid]=0; }
  if (tid==4) inbF=0;
  if (role==0) h16s[i][15][lane]=0;   // h(-1)=0
  __syncthreads();

  uint4 qq0,qq1,qq2,qq3;

  if (role<2) {
    // ================= crit pair (CA low / CB high) =================
    const int ho = role*16;
    h2 wr[16],wz[16],wn[16],mr[16],mz[16];
    #pragma unroll
    for (int d=0;d<16;d++){
      wr[d]=H2(WH16[lane*32+ho+d]);
      wz[d]=H2(WH16[(64+lane)*32+ho+d]);
      wn[d]=H2(WH16[(128+lane)*32+ho+d]);
      mr[d]=H2(WM16[lane*32+ho+d]);
      mz[d]=H2(WM16[(64+lane)*32+ho+d]);
    }
    if (role==0){
      // ---- CA: combiner + gates ----
      const float bhr=b_hh[lane], bhz=b_hh[64+lane], bhn=b_hh[128+lane];
      float hreg=0.f;
      for (int c=0;c<256;c++){
        if (((c&3)==0) && i<3){ POLLGE(flgA[i+1], c-8); POLLGE(flgHB[i+1], c-8); }  // h16 ring (margin 4)
        if ((c&3)==0) POLLGE(ioPr[i], c-4);                                         // h32 ring
        LOADHALF(&h16s[i][(c+15)&15][0])
        float ghr=bhr, ghz=bhz, ghn=bhn;
        DOT16(ghr,wr) DOT16(ghz,wz) DOT16(ghn,wn)
        POLLGE(flgA[i], c+2);                 // gi[c] + a16[c] ready
        float4 gv = gi4s[i][c&3][lane];
        LOADHALF(&a16s[i][c&7][0])
        float g2r=0.f, g2z=0.f;
        DOT16(g2r,mr) DOT16(g2z,mz)
        POLLGE(flgCB[i], c+1);
        const float* cbp = &cb2ca[i][c&1][0][lane];
        float ph0=cbp[0], ph1=cbp[64], ph2=cbp[128], ph3=cbp[192], ph4=cbp[256];
        float rg = SIG(gv.x + g2r+ph3 + ghr+ph0);
        float zg = SIG(gv.y + g2z+ph4 + ghz+ph1);
        float xn = gv.z + rg*(ghn+ph2);
        float e2 = __expf(2.f*xn);
        float ng = 1.f-2.f/(e2+1.f);
        hreg = zg*hreg + (1.f-zg)*ng;
        h16s[i][c&15][lane]=F2H(hreg);
        h32s[i][c&7][lane]=hreg;
        asm volatile("s_waitcnt lgkmcnt(0)" ::: "memory");
        if (lane==0) *(volatile int*)&flgH[i]=c+1;
      }
    } else {
      // ---- CB: high-half partials (+ chain0 copyout if i==0) ----
      int cp0=0;
      float* hfo0 = h_full + (size_t)(b*65+tg*4+1)*16384;   // chain 0 output (t=4tg)
      for (int c=0;c<256;c++){
        if (c>0) POLLGE(flgH[i], c);          // row c-1 ready (also frees cb2ca slot)
        LOADHALF(&h16s[i][(c+15)&15][32])
        float ghr=0.f, ghz=0.f, ghn=0.f;
        DOT16(ghr,wr) DOT16(ghz,wz) DOT16(ghn,wn)
        POLLGE(flgA[i], c+1);                 // a16[c]
        LOADHALF(&a16s[i][c&7][32])
        float g2r=0.f, g2z=0.f;
        DOT16(g2r,mr) DOT16(g2z,mz)
        float* cbp = &cb2ca[i][c&1][0][lane];
        cbp[0]=ghr; cbp[64]=ghz; cbp[128]=ghn; cbp[192]=g2r; cbp[256]=g2z;
        asm volatile("s_waitcnt lgkmcnt(0)" ::: "memory");
        if (lane==0) *(volatile int*)&flgCB[i]=c+1;
        if (i==0){
          int av=*(volatile int*)&flgH[0]; asm volatile("":::"memory");
          int lim=cp0+2; if (av>lim) av=lim;
          while (cp0<av){
            float hv=h32s[0][cp0&7][lane];
            hfo0[cp0*64+lane]=hv; cp0++;
            if ((cp0&3)==0 && lane==0) *(volatile int*)&ioPr[0]=cp0;
          }
        }
      }
      if (i==0){
        while (cp0<256){
          POLLGE(flgH[0], cp0+1);
          float hv=h32s[0][cp0&7][lane];
          hfo0[cp0*64+lane]=hv; cp0++;
          if ((cp0&3)==0 && lane==0) *(volatile int*)&ioPr[0]=cp0;
        }
      }
    }
  } else {
    // ================= helper pair (HA low+combiner / HB high+I/O) =================
    const int ho = (role-2)*16;
    h2 u0[16],u1[16],u2[16],u3[16],w2[16];
    #pragma unroll
    for (int d=0;d<16;d++){
      u0[d]=H2(U16[lane*32+ho+d]);
      u1[d]=H2(U16[(64+lane)*32+ho+d]);
      u2[d]=H2(U16[(128+lane)*32+ho+d]);
      u3[d]=H2(U16[(192+lane)*32+ho+d]);
      w2[d]=H2(WM16[(128+lane)*32+ho+d]);
    }
    const int qrow=q[b*64+t];
    if (role==2){
      // ---- HA ----
      const float cbr=cb[lane], cbz=cb[64+lane], cbn=cb[128+lane];
      const float xr=xe1[(b*64+t)*64+lane];
      float e1cur=(qrow==0)? xr : qe1[lane];
      float prP=0.f,pzP=0.f,pnP=0.f;
      for (int s=0;s<=256;s++){
        POLLGE(flgH[i], s-4);    // v8 FIX: gi4 depth-4 reuse -> CA consumed gi[s-5] (every iter)
        POLLGE(flgCB[i], s-7);   // v8 FIX: a16 depth-8 reuse -> CB consumed a16[s-8] (every iter)
        float e1n = (s<255)? (((s+1)==qrow)? xr : qe1[(s+1)*64+lane]) : 0.f;
        float m1=0.f,pr=0.f,pz=0.f,pn=0.f;
        if (s<=255){
          if (i==0) POLLGE(inbF, s+1); else POLLGE(flgH[i-1], s+1);
          LOADHALF( (i==0)? &inbox[s&15][0] : &h16s[i-1][s&15][0] )
          DOT16(m1,u0) DOT16(pr,u1) DOT16(pz,u2) DOT16(pn,u3)
        }
        float g2n=0.f;
        if (s>=1){ LOADHALF(&a16s[i][(s-1)&7][0]) DOT16(g2n,w2) }
        POLLGE(flgHB[i], s+1);
        const float* hbp=&hb2ha[i][s&1][0][lane];
        float m1h=hbp[0],prh=hbp[64],pzh=hbp[128],pnh=hbp[192],g2nh=hbp[256];
        if (s<=255){
          float av=fmaxf(e1cur+m1+m1h, 0.f);
          a16s[i][s&7][lane]=F2H(av);
        }
        if (s>=1) gi4s[i][(s-1)&3][lane]=make_float4(prP,pzP,pnP+g2n+g2nh,0.f);
        asm volatile("s_waitcnt lgkmcnt(0)" ::: "memory");
        if (lane==0) *(volatile int*)&flgA[i]=s+1;
        prP=cbr+pr+prh; pzP=cbz+pz+pzh; pnP=cbn+pn+pnh;
        e1cur=e1n;
      }
    } else {
      // ---- HB: high partials + inbox(i==0) + copyout(i>=1) ----
      const float* hfp = h_full + (size_t)(b*65+tg*4)*16384;
      const unsigned* hfpu = (const unsigned*)hfp;
      unsigned* gfp = gflag + (b*16+tg-1);
      unsigned* gfc = gflag + (b*16+tg);
      float* hfo = h_full + (size_t)(b*65+t+1)*16384;
      unsigned* hfoU = (unsigned*)hfo;
      const bool pubG = (i==3) && (tg<15);
      unsigned gv=0; int pf=0, cp=0;

      for (int s=0;s<=256;s++){
        // inbox prefetch (chain 0 only)
        if (i==0 && pf<256){
          int want=s+13; if (want>256) want=256;
          if (tg==0){
            while (pf<want){
              int k=want-pf; if (k>4) k=4;
              float r0=hfp[(pf+0)*64+lane];
              float r1=(k>1)?hfp[(pf+1)*64+lane]:0.f;
              float r2=(k>2)?hfp[(pf+2)*64+lane]:0.f;
              float r3=(k>3)?hfp[(pf+3)*64+lane]:0.f;
              inbox[(pf+0)&15][lane]=F2H(r0);
              if(k>1) inbox[(pf+1)&15][lane]=F2H(r1);
              if(k>2) inbox[(pf+2)&15][lane]=F2H(r2);
              if(k>3) inbox[(pf+3)&15][lane]=F2H(r3);
              pf+=k;
            }
          } else {
            if ((int)gv < want) gv=__hip_atomic_load(gfp,__ATOMIC_RELAXED,__HIP_MEMORY_SCOPE_AGENT);
            for (;;){
              int can=(int)gv; if (can>want) can=want;
              while (pf<can){
                int k=can-pf; if (k>4) k=4;
                unsigned a0,a1=0,a2=0,a3=0;
                a0=__hip_atomic_load(&hfpu[(pf+0)*64+lane],__ATOMIC_RELAXED,__HIP_MEMORY_SCOPE_AGENT);
                if(k>1) a1=__hip_atomic_load(&hfpu[(pf+1)*64+lane],__ATOMIC_RELAXED,__HIP_MEMORY_SCOPE_AGENT);
                if(k>2) a2=__hip_atomic_load(&hfpu[(pf+2)*64+lane],__ATOMIC_RELAXED,__HIP_MEMORY_SCOPE_AGENT);
                if(k>3) a3=__hip_atomic_load(&hfpu[(pf+3)*64+lane],__ATOMIC_RELAXED,__HIP_MEMORY_SCOPE_AGENT);
                union{unsigned u; float f;} c0,c1,c2,c3;
                c0.u=a0; c1.u=a1; c2.u=a2; c3.u=a3;
                inbox[(pf+0)&15][lane]=F2H(c0.f);
                if(k>1) inbox[(pf+1)&15][lane]=F2H(c1.f);
                if(k>2) inbox[(pf+2)&15][lane]=F2H(c2.f);
                if(k>3) inbox[(pf+3)&15][lane]=F2H(c3.f);
                pf+=k;
              }
              if (pf>s || pf>=256) break;     // need rows up to s
              gv=__hip_atomic_load(gfp,__ATOMIC_RELAXED,__HIP_MEMORY_SCOPE_AGENT);
              if ((int)gv<=s) __builtin_amdgcn_s_sleep(2);
            }
          }
          asm volatile("s_waitcnt lgkmcnt(0)" ::: "memory");
          if (lane==0) *(volatile int*)&inbF=pf;
        }
        float m1=0.f,pr=0.f,pz=0.f,pn=0.f;
        if (s<=255){
          if (i>0) POLLGE(flgH[i-1], s+1);
          LOADHALF( (i==0)? &inbox[s&15][32] : &h16s[i-1][s&15][32] )
          DOT16(m1,u0) DOT16(pr,u1) DOT16(pz,u2) DOT16(pn,u3)
        }
        float g2n=0.f;
        if (s>=1){
          POLLGE(flgA[i], s);
          LOADHALF(&a16s[i][(s-1)&7][32])
          DOT16(g2n,w2)
        }
        float* hbp=&hb2ha[i][s&1][0][lane];
        hbp[0]=m1; hbp[64]=pr; hbp[128]=pz; hbp[192]=pn; hbp[256]=g2n;
        asm volatile("s_waitcnt lgkmcnt(0)" ::: "memory");
        if (lane==0) *(volatile int*)&flgHB[i]=s+1;
        // copyout (chains 1..3)
        if (i>=1){
          int av=*(volatile int*)&flgH[i]; asm volatile("":::"memory");
          int lim=cp+2; if (av>lim) av=lim;
          while (cp<av){
            float hv=h32s[i][cp&7][lane];
            if (i==3){ union{float f; unsigned u;} cu; cu.f=hv;
              __hip_atomic_store(&hfoU[cp*64+lane],cu.u,__ATOMIC_RELAXED,__HIP_MEMORY_SCOPE_AGENT);
            } else hfo[cp*64+lane]=hv;
            cp++;
            if ((cp&3)==0 && lane==0) *(volatile int*)&ioPr[i]=cp;
            if (pubG && (cp&7)==0){
              asm volatile("s_waitcnt vmcnt(0)" ::: "memory");
              if (lane==0) __hip_atomic_store(gfc,(unsigned)cp,__ATOMIC_RELAXED,__HIP_MEMORY_SCOPE_AGENT);
            }
          }
        }
      }
      if (i>=1){
        while (cp<256){
          POLLGE(flgH[i], cp+1);
          float hv=h32s[i][cp&7][lane];
          if (i==3){ union{float f; unsigned u;} cu; cu.f=hv;
            __hip_atomic_store(&hfoU[cp*64+lane],cu.u,__ATOMIC_RELAXED,__HIP_MEMORY_SCOPE_AGENT);
          } else hfo[cp*64+lane]=hv;
          cp++;
          if ((cp&3)==0 && lane==0) *(volatile int*)&ioPr[i]=cp;
          if (pubG && (cp&7)==0){
            asm volatile("s_waitcnt vmcnt(0)" ::: "memory");
            if (lane==0) __hip_atomic_store(gfc,(unsigned)cp,__ATOMIC_RELAXED,__HIP_MEMORY_SCOPE_AGENT);
          }
        }
      }
    }
  }
}

// ================= hw[b][u][c] = h_full[b][u][c][:] . out_w =================
__global__ __launch_bounds__(256) void kHw(const float* __restrict__ h_full,
    const float* __restrict__ out_w, float* __restrict__ hw)
{
  __shared__ float ow[64];
  if (threadIdx.x < 64) ow[threadIdx.x] = out_w[threadIdx.x];
  __syncthreads();
  const int blk = blockIdx.x, c = threadIdx.x;
  const float* hp = h_full + ((size_t)blk*256 + c)*64;
  float s = 0.f;
  #pragma unroll
  for (int f=0; f<64; f++) s += hp[f]*ow[f];
  hw[blk*256+c] = s;
}

// ================= readout =================
__global__ __launch_bounds__(256) void kY(const int* __restrict__ q,
    const float* __restrict__ ws, const float* __restrict__ bias,
    const float* __restrict__ theta, float* __restrict__ y)
{
  const float* G  = ws + WS_G;
  const float* hw = ws + WS_HW;
  const int b = blockIdx.x >> 2, tq = blockIdx.x & 3;
  const int c = threadIdx.x;
  __shared__ float siml[64][256];
  for (int u=0; u<64; u++) {
    int qq = q[b*64+u];
    siml[u][c] = G[qq*256+c];
  }
  __syncthreads();
  const float rate = __expf(theta[0]);
  const float bv = bias[c];
  const float* hwb = hw + b*65*256;
  for (int tt=0; tt<16; tt++) {
    const int t = tq*16+tt;
    float mx = -1e30f;
    for (int u=0; u<=t; u++) {
      float s = __expf(-rate*(float)(t-u))*siml[u][c];
      mx = fmaxf(mx, s);
    }
    float se = 0.f, sw = 0.f;
    for (int u=0; u<=t; u++) {
      float s = __expf(-rate*(float)(t-u))*siml[u][c];
      float e = __expf(s-mx);
      se += e; sw += e*hwb[u*256+c];
    }
    float lg = hwb[(t+1)*256+c] + sw/se + bv;
    y[(b*64+t)*256+c] = 1.f/(1.f+__expf(-lg));
  }
}

extern "C" void kernel_launch(void* const* d_in, const int* in_sizes, int n_in,
                              void* d_out, int out_size, void* d_ws, size_t ws_size,
                              hipStream_t stream)
{
  (void)in_sizes; (void)n_in; (void)out_size; (void)ws_size;
  const int*   q      = (const int*)  d_in[0];
  const int*   r      = (const int*)  d_in[1];
  const float* x_emb  = (const float*)d_in[2];
  const float* q_emb  = (const float*)d_in[3];
  const float* init_h = (const float*)d_in[4];
  const float* w1     = (const float*)d_in[5];
  const float* b1     = (const float*)d_in[6];
  const float* w2     = (const float*)d_in[7];
  const float* b2     = (const float*)d_in[8];
  const float* w_ih   = (const float*)d_in[9];
  const float* w_hh   = (const float*)d_in[10];
  const float* b_ih   = (const float*)d_in[11];
  const float* b_hh   = (const float*)d_in[12];
  const float* bias   = (const float*)d_in[13];
  const float* out_w  = (const float*)d_in[14];
  const float* theta  = (const float*)d_in[15];

  float* out    = (float*)d_out;
  float* y      = out;
  float* h_full = out + 262144;
  float* ws     = (float*)d_ws;

  hipMemsetAsync((unsigned*)ws + WS_GFLAG, 0, 256*sizeof(unsigned), stream);
  kPrep<<<1681,256,0,stream>>>(q,r,x_emb,q_emb,init_h,w1,b1,w2,b2,w_ih,w_hh,b_ih,ws,h_full);
  {
    void* ka[] = { (void*)&q, (void*)&b_hh, (void*)&ws, (void*)&h_full };
    hipError_t e = hipLaunchCooperativeKernel((const void*)kA, dim3(256), dim3(1024), ka, 0, stream);
    if (e != hipSuccess) {
      kA<<<dim3(256),dim3(1024),0,stream>>>(q,b_hh,ws,h_full);
    }
  }
  kHw<<<1040,256,0,stream>>>(h_full, out_w, ws + WS_HW);
  kY<<<64,256,0,stream>>>(q, ws, bias, theta, y);
}

// Round 9
// 802.356 us; speedup vs baseline: 1.4313x; 1.3064x over previous
//
#include <hip/hip_runtime.h>
#include <math.h>

// ---- ws layout (float-slot offsets) ----
#define WS_CB     0         // 192
#define WS_QE1    192       // 16384
#define WS_XE1    16576     // 65536
#define WS_G      82112     // 65536
#define WS_HW     147648    // 266240
#define WS_U16    413888    // 8192 u32
#define WS_WHH16  422080    // 6144 u32
#define WS_W2M16  428224    // 6144 u32
#define WS_GFLAG  442560    // 256 u32

typedef _Float16 h2 __attribute__((ext_vector_type(2)));

#if defined(__has_builtin)
#if __has_builtin(__builtin_amdgcn_fdot2)
#define FDOT2(a,b,c) __builtin_amdgcn_fdot2((a),(b),(c),false)
#endif
#endif
#ifndef FDOT2
__device__ inline float fdot2_sw(h2 a, h2 b, float c){ return c + (float)a[0]*(float)b[0] + (float)a[1]*(float)b[1]; }
#define FDOT2(a,b,c) fdot2_sw((a),(b),(c))
#endif

__device__ inline h2 H2(unsigned u){ union{unsigned x; h2 h;} v; v.x=u; return v.h; }
__device__ inline unsigned short F2H(float f){ union{_Float16 h; unsigned short s;} v; v.h=(_Float16)f; return v.s; }
__device__ inline unsigned PACK2(float a, float b){ return (unsigned)F2H(a) | ((unsigned)F2H(b)<<16); }

// ---- named-register machinery ----
#define F32(X,A) X(A,0)X(A,1)X(A,2)X(A,3)X(A,4)X(A,5)X(A,6)X(A,7)X(A,8)X(A,9)X(A,10)X(A,11)X(A,12)X(A,13)X(A,14)X(A,15)X(A,16)X(A,17)X(A,18)X(A,19)X(A,20)X(A,21)X(A,22)X(A,23)X(A,24)X(A,25)X(A,26)X(A,27)X(A,28)X(A,29)X(A,30)X(A,31)
#define DCL1(W,K) h2 W##_##K;
#define DECLW(W) F32(DCL1,W)
#define LD1(W,K) W##_##K = H2(_wb[K]);
#define LOADW(W,BASE) { const unsigned* _wb=(BASE); F32(LD1,W) }
// IN-LOOP opaque pin: executed every iteration -> weight defs cannot be
// rematerialized into the loop; values must stay register-resident (or
// spill to scratch, which is observable). 8 operands per asm statement.
#define PINW(W) \
  asm volatile("" : "+v"(W##_0),"+v"(W##_1),"+v"(W##_2),"+v"(W##_3),"+v"(W##_4),"+v"(W##_5),"+v"(W##_6),"+v"(W##_7)); \
  asm volatile("" : "+v"(W##_8),"+v"(W##_9),"+v"(W##_10),"+v"(W##_11),"+v"(W##_12),"+v"(W##_13),"+v"(W##_14),"+v"(W##_15)); \
  asm volatile("" : "+v"(W##_16),"+v"(W##_17),"+v"(W##_18),"+v"(W##_19),"+v"(W##_20),"+v"(W##_21),"+v"(W##_22),"+v"(W##_23)); \
  asm volatile("" : "+v"(W##_24),"+v"(W##_25),"+v"(W##_26),"+v"(W##_27),"+v"(W##_28),"+v"(W##_29),"+v"(W##_30),"+v"(W##_31));
#define DT1(W,K) _acc = FDOT2(W##_##K, H2(RC##K), _acc);
#define DOTW(ACC,W) { float _acc=(ACC); F32(DT1,W) (ACC)=_acc; }
#define RC0 qq0.x
#define RC1 qq0.y
#define RC2 qq0.z
#define RC3 qq0.w
#define RC4 qq1.x
#define RC5 qq1.y
#define RC6 qq1.z
#define RC7 qq1.w
#define RC8 qq2.x
#define RC9 qq2.y
#define RC10 qq2.z
#define RC11 qq2.w
#define RC12 qq3.x
#define RC13 qq3.y
#define RC14 qq3.z
#define RC15 qq3.w
#define RC16 qq4.x
#define RC17 qq4.y
#define RC18 qq4.z
#define RC19 qq4.w
#define RC20 qq5.x
#define RC21 qq5.y
#define RC22 qq5.z
#define RC23 qq5.w
#define RC24 qq6.x
#define RC25 qq6.y
#define RC26 qq6.z
#define RC27 qq6.w
#define RC28 qq7.x
#define RC29 qq7.y
#define RC30 qq7.z
#define RC31 qq7.w
#define LOADROW(P) { const uint4* _rp=(const uint4*)(P); qq0=_rp[0];qq1=_rp[1];qq2=_rp[2];qq3=_rp[3];qq4=_rp[4];qq5=_rp[5];qq6=_rp[6];qq7=_rp[7]; }

// plain volatile LDS flag poll (DS ops are per-wave in-order; no cache ops)
#define POLLGE(F,T) do{ while(*(volatile int*)&(F) < (T)) {} asm volatile("" ::: "memory"); }while(0)

// ================= precompute =================
__global__ __launch_bounds__(256) void kPrep(
    const int* __restrict__ q, const int* __restrict__ r,
    const float* __restrict__ x_emb, const float* __restrict__ q_emb,
    const float* __restrict__ init_h, const float* __restrict__ w1,
    const float* __restrict__ b1, const float* __restrict__ w2,
    const float* __restrict__ b2, const float* __restrict__ w_ih,
    const float* __restrict__ w_hh, const float* __restrict__ b_ih,
    float* __restrict__ ws, float* __restrict__ h_full)
{
  int idx = blockIdx.x*256 + threadIdx.x;
  unsigned* wsu = (unsigned*)ws;
  if (idx < 192) {
    int g = idx; float s = b_ih[g];
    for (int j=0;j<64;j++) s += b2[j]*w_ih[g*128+j];
    ws[WS_CB+g] = s;
  } else if (idx < 16576) {
    int e = idx-192; int c = e>>6, i = e&63;
    float s = b1[i];
    for (int k=0;k<64;k++) s += q_emb[c*64+k]*w1[(64+k)*64+i];
    ws[WS_QE1+e] = s;
  } else if (idx < 82112) {
    int e = idx-16576; int bt = e>>6, i = e&63;
    int row = q[bt] + 256*r[bt];
    float s = b1[i];
    for (int k=0;k<64;k++) s += x_emb[row*64+k]*w1[(64+k)*64+i];
    ws[WS_XE1+e] = s;
  } else if (idx < 147648) {
    int e = idx-82112; int a = e>>8, cc = e&255;
    float s = 0.f;
    for (int d=0;d<64;d++) s += q_emb[a*64+d]*q_emb[cc*64+d];
    ws[WS_G+e] = s;
  } else if (idx < 409792) {
    int e = idx-147648; int bb = e>>14, cf = e&16383;
    h_full[(size_t)bb*65*16384 + cf] = init_h[cf];
  } else if (idx < 417984) {
    int e = idx-409792; int rr = e>>5, d = e&31;
    float v0, v1;
    if (rr < 64) { v0 = w1[(2*d)*64+rr];   v1 = w1[(2*d+1)*64+rr]; }
    else { int g = rr-64; v0 = w_ih[g*128+64+2*d]; v1 = w_ih[g*128+64+2*d+1]; }
    wsu[WS_U16+e] = PACK2(v0,v1);
  } else if (idx < 424128) {
    int e = idx-417984; int g = e>>5, d = e&31;
    wsu[WS_WHH16+e] = PACK2(w_hh[g*64+2*d], w_hh[g*64+2*d+1]);
  } else if (idx < 430272) {
    int e = idx-424128; int g = e>>5, d = e&31;
    float s0=0.f, s1=0.f;
    for (int j=0;j<64;j++){ float wij = w_ih[g*128+j]; s0 += w2[(2*d)*64+j]*wij; s1 += w2[(2*d+1)*64+j]*wij; }
    wsu[WS_W2M16+e] = PACK2(s0,s1);
  }
}

// ================= wavefront recurrence v9 = v4 structure + IN-LOOP pins =================
// 256 WGs x 512 threads, 1 WG/CU (8 waves = 2/SIMD -> 256-VGPR budget).
// waves 0-3: crit (GRU gates, 160 pinned weight regs). waves 4-7: helper (U-dots + I/O).
__global__ __launch_bounds__(512) __attribute__((amdgpu_waves_per_eu(2,2)))
void kA(
    const int* __restrict__ q, const float* __restrict__ b_hh,
    float* __restrict__ ws, float* __restrict__ h_full)
{
  __shared__ __align__(16) unsigned short h16s[4][16][64];
  __shared__ __align__(16) unsigned short a16s[4][8][64];
  __shared__ __align__(16) unsigned short inbox[16][64];
  __shared__ __align__(16) float4 gi4s[4][8][64];
  __shared__ float h32s[4][8][64];
  __shared__ int flgH[4], p2s[4], ioPr[4];

  const int bid=blockIdx.x, b=bid&15, tg=bid>>4;
  const int tid=threadIdx.x, w=tid>>6, lane=tid&63;
  const bool isA = (w<4);
  const int i = isA? w : w-4;
  const int t = tg*4 + i;

  const unsigned* U16  = (const unsigned*)ws + WS_U16;
  const unsigned* WH16 = (const unsigned*)ws + WS_WHH16;
  const unsigned* WM16 = (const unsigned*)ws + WS_W2M16;
  const float* qe1 = ws + WS_QE1;
  const float* xe1 = ws + WS_XE1;
  const float* cb  = ws + WS_CB;
  unsigned* gflag = (unsigned*)ws + WS_GFLAG;

  if (tid<4){ flgH[tid]=0; p2s[tid]=0; ioPr[tid]=0; }
  if (isA) h16s[i][15][lane]=0;   // h(-1)=0
  __syncthreads();

  uint4 qq0,qq1,qq2,qq3,qq4,qq5,qq6,qq7;

  if (isA) {
    // ---- crit wave: gh dots + a.W2m_{r,z} + gates ----
    DECLW(wrq) DECLW(wzq) DECLW(wnq) DECLW(mrq) DECLW(mzq)
    LOADW(wrq, WH16+lane*32)
    LOADW(wzq, WH16+(64+lane)*32)
    LOADW(wnq, WH16+(128+lane)*32)
    LOADW(mrq, WM16+lane*32)
    LOADW(mzq, WM16+(64+lane)*32)
    const float bhr=b_hh[lane], bhz=b_hh[64+lane], bhn=b_hh[128+lane];
    float hreg=0.f;
    for (int c=0;c<256;c++){
      // in-loop pins: weights must be live in registers here, every iteration
      PINW(wrq) PINW(wzq) PINW(wnq) PINW(mrq) PINW(mzq)
      if (((c&7)==0) && i<3) POLLGE(p2s[i+1], c-12);  // h16 ring reuse (batched)
      if ((c&3)==0) POLLGE(ioPr[i], c-4);             // h32 ring reuse
      LOADROW(h16s[i][(c+15)&15])                     // own row c-1 (no flag dep)
      float ghr=bhr, ghz=bhz, ghn=bhn;
      DOTW(ghr,wrq) DOTW(ghz,wzq) DOTW(ghn,wnq)
      POLLGE(p2s[i], c+1);                            // gi[c]+a16[c] ready
      float4 gv = gi4s[i][c&7][lane];
      LOADROW(a16s[i][c&7])
      float g2r=0.f, g2z=0.f;
      DOTW(g2r,mrq) DOTW(g2z,mzq)
      float rg = 1.f/(1.f+__expf(-(gv.x+g2r+ghr)));
      float zg = 1.f/(1.f+__expf(-(gv.y+g2z+ghz)));
      float xn = gv.z + rg*ghn;
      float e2 = __expf(2.f*xn);
      float ng = 1.f-2.f/(e2+1.f);
      hreg = zg*hreg + (1.f-zg)*ng;
      h16s[i][c&15][lane]=F2H(hreg);
      h32s[i][c&7][lane]=hreg;
      asm volatile("s_waitcnt lgkmcnt(0)" ::: "memory");
      if (lane==0) *(volatile int*)&flgH[i]=c+1;
    }
  } else {
    // ---- helper wave: U-dots + a.W2m_n (lag 1) + opportunistic I/O ----
    DECLW(u0q) DECLW(u1q) DECLW(u2q) DECLW(u3q) DECLW(w2q)
    LOADW(u0q, U16+lane*32)
    LOADW(u1q, U16+(64+lane)*32)
    LOADW(u2q, U16+(128+lane)*32)
    LOADW(u3q, U16+(192+lane)*32)
    LOADW(w2q, WM16+(128+lane)*32)
    const float cbr=cb[lane], cbz=cb[64+lane], cbn=cb[128+lane];
    const int qrow=q[b*64+t];
    const float xr=xe1[(b*64+t)*64+lane];
    const float* hfp = h_full + (size_t)(b*65+4*tg)*16384;
    float* hfoF = h_full + (size_t)(b*65+t+1)*16384;
    unsigned* hfoU = (unsigned*)hfoF;
    unsigned* gfp = gflag + (b*16+tg-1);
    unsigned* gfc = gflag + (b*16+tg);
    const bool pubG = (i==3) && (tg<15);
    unsigned gv=0; int pfrow=0, cp=0;
    float e1cur = (qrow==0)? xr : qe1[lane];
    float prP=0.f,pzP=0.f,pnP=0.f;

    for (int s=0;s<=256;s++){
      PINW(u0q) PINW(u1q) PINW(u2q) PINW(u3q) PINW(w2q)
      if ((s&3)==0) POLLGE(flgH[i], s-4);   // a16/gi ring reuse (depth 8)
      float e1n=0.f;
      if (s<255) e1n = ((s+1)==qrow)? xr : qe1[(s+1)*64+lane];
      float pr=0.f,pz=0.f,pn=0.f;
      if (s<=255){
        if (i==0){
          // blocking fill to row s, opportunistic 1 ahead (depth<=8)
          while (pfrow<=s){
            if (tg>0){
              while (gv < (unsigned)(pfrow+1)){
                gv = __hip_atomic_load(gfp,__ATOMIC_RELAXED,__HIP_MEMORY_SCOPE_AGENT);
                if (gv < (unsigned)(pfrow+1)) __builtin_amdgcn_s_sleep(1);
              }
              union{unsigned u; float f;} cv;
              cv.u = __hip_atomic_load((const unsigned*)&hfp[pfrow*64+lane],__ATOMIC_RELAXED,__HIP_MEMORY_SCOPE_AGENT);
              inbox[pfrow&15][lane]=F2H(cv.f);
            } else {
              inbox[pfrow&15][lane]=F2H(hfp[pfrow*64+lane]);
            }
            pfrow++;
          }
          if (pfrow<=s+8){
            bool can=(tg==0);
            if (tg>0){
              if (gv>=(unsigned)(pfrow+1)) can=true;
              else if ((s&1)==0){ gv=__hip_atomic_load(gfp,__ATOMIC_RELAXED,__HIP_MEMORY_SCOPE_AGENT); can = gv>=(unsigned)(pfrow+1); }
            }
            if (can){
              if (tg>0){
                union{unsigned u; float f;} cv;
                cv.u = __hip_atomic_load((const unsigned*)&hfp[pfrow*64+lane],__ATOMIC_RELAXED,__HIP_MEMORY_SCOPE_AGENT);
                inbox[pfrow&15][lane]=F2H(cv.f);
              } else {
                inbox[pfrow&15][lane]=F2H(hfp[pfrow*64+lane]);
              }
              pfrow++;
            }
          }
        } else {
          POLLGE(flgH[i-1], s+1);
        }
        LOADROW( (i==0)? inbox[s&15] : h16s[i-1][s&15] )
        float m1=e1cur; pr=cbr; pz=cbz; pn=cbn;
        DOTW(m1,u0q) DOTW(pr,u1q) DOTW(pz,u2q) DOTW(pn,u3q)
        a16s[i][s&7][lane]=F2H(fmaxf(m1,0.f));
      }
      if (s>=1){
        LOADROW(a16s[i][(s-1)&7])
        float g2n=0.f; DOTW(g2n,w2q)
        gi4s[i][(s-1)&7][lane]=make_float4(prP,pzP,pnP+g2n,0.f);
      }
      asm volatile("s_waitcnt lgkmcnt(0)" ::: "memory");
      if (lane==0) *(volatile int*)&p2s[i]=s;
      prP=pr; pzP=pz; pnP=pn; e1cur=e1n;
      // opportunistic copyout (<=2 rows/step)
      int av=*(volatile int*)&flgH[i];
      asm volatile("" ::: "memory");
      int nc=0;
      while (cp<av && nc<2){
        float hv=h32s[i][cp&7][lane];
        if (i==3){ union{float f; unsigned u;} cu; cu.f=hv;
          __hip_atomic_store(&hfoU[cp*64+lane],cu.u,__ATOMIC_RELAXED,__HIP_MEMORY_SCOPE_AGENT);
        } else hfoF[cp*64+lane]=hv;
        cp++; nc++;
        if ((cp&3)==0){
          *(volatile int*)&ioPr[i]=cp;
          if (pubG){ asm volatile("s_waitcnt vmcnt(0)" ::: "memory");
            if (lane==0) __hip_atomic_store(gfc,(unsigned)cp,__ATOMIC_RELAXED,__HIP_MEMORY_SCOPE_AGENT); }
        }
      }
    }
    // drain remaining rows
    while (cp<256){
      POLLGE(flgH[i], cp+1);
      float hv=h32s[i][cp&7][lane];
      if (i==3){ union{float f; unsigned u;} cu; cu.f=hv;
        __hip_atomic_store(&hfoU[cp*64+lane],cu.u,__ATOMIC_RELAXED,__HIP_MEMORY_SCOPE_AGENT);
      } else hfoF[cp*64+lane]=hv;
      cp++;
      if ((cp&3)==0){
        *(volatile int*)&ioPr[i]=cp;
        if (pubG){ asm volatile("s_waitcnt vmcnt(0)" ::: "memory");
          if (lane==0) __hip_atomic_store(gfc,(unsigned)cp,__ATOMIC_RELAXED,__HIP_MEMORY_SCOPE_AGENT); }
      }
    }
  }
}

// ================= hw[b][u][c] = h_full[b][u][c][:] . out_w =================
__global__ __launch_bounds__(256) void kHw(const float* __restrict__ h_full,
    const float* __restrict__ out_w, float* __restrict__ hw)
{
  __shared__ float ow[64];
  if (threadIdx.x < 64) ow[threadIdx.x] = out_w[threadIdx.x];
  __syncthreads();
  const int blk = blockIdx.x, c = threadIdx.x;
  const float* hp = h_full + ((size_t)blk*256 + c)*64;
  float s = 0.f;
  #pragma unroll
  for (int f=0; f<64; f++) s += hp[f]*ow[f];
  hw[blk*256+c] = s;
}

// ================= readout =================
__global__ __launch_bounds__(256) void kY(const int* __restrict__ q,
    const float* __restrict__ ws, const float* __restrict__ bias,
    const float* __restrict__ theta, float* __restrict__ y)
{
  const float* G  = ws + WS_G;
  const float* hw = ws + WS_HW;
  const int b = blockIdx.x >> 2, tq = blockIdx.x & 3;
  const int c = threadIdx.x;
  __shared__ float siml[64][256];
  for (int u=0; u<64; u++) {
    int qq = q[b*64+u];
    siml[u][c] = G[qq*256+c];
  }
  __syncthreads();
  const float rate = __expf(theta[0]);
  const float bv = bias[c];
  const float* hwb = hw + b*65*256;
  for (int tt=0; tt<16; tt++) {
    const int t = tq*16+tt;
    float mx = -1e30f;
    for (int u=0; u<=t; u++) {
      float s = __expf(-rate*(float)(t-u))*siml[u][c];
      mx = fmaxf(mx, s);
    }
    float se = 0.f, sw = 0.f;
    for (int u=0; u<=t; u++) {
      float s = __expf(-rate*(float)(t-u))*siml[u][c];
      float e = __expf(s-mx);
      se += e; sw += e*hwb[u*256+c];
    }
    float lg = hwb[(t+1)*256+c] + sw/se + bv;
    y[(b*64+t)*256+c] = 1.f/(1.f+__expf(-lg));
  }
}

extern "C" void kernel_launch(void* const* d_in, const int* in_sizes, int n_in,
                              void* d_out, int out_size, void* d_ws, size_t ws_size,
                              hipStream_t stream)
{
  (void)in_sizes; (void)n_in; (void)out_size; (void)ws_size;
  const int*   q      = (const int*)  d_in[0];
  const int*   r      = (const int*)  d_in[1];
  const float* x_emb  = (const float*)d_in[2];
  const float* q_emb  = (const float*)d_in[3];
  const float* init_h = (const float*)d_in[4];
  const float* w1     = (const float*)d_in[5];
  const float* b1     = (const float*)d_in[6];
  const float* w2     = (const float*)d_in[7];
  const float* b2     = (const float*)d_in[8];
  const float* w_ih   = (const float*)d_in[9];
  const float* w_hh   = (const float*)d_in[10];
  const float* b_ih   = (const float*)d_in[11];
  const float* b_hh   = (const float*)d_in[12];
  const float* bias   = (const float*)d_in[13];
  const float* out_w  = (const float*)d_in[14];
  const float* theta  = (const float*)d_in[15];

  float* out    = (float*)d_out;
  float* y      = out;
  float* h_full = out + 262144;
  float* ws     = (float*)d_ws;

  hipMemsetAsync((unsigned*)ws + WS_GFLAG, 0, 256*sizeof(unsigned), stream);
  kPrep<<<1681,256,0,stream>>>(q,r,x_emb,q_emb,init_h,w1,b1,w2,b2,w_ih,w_hh,b_ih,ws,h_full);
  {
    void* ka[] = { (void*)&q, (void*)&b_hh, (void*)&ws, (void*)&h_full };
    hipError_t e = hipLaunchCooperativeKernel((const void*)kA, dim3(256), dim3(512), ka, 0, stream);
    if (e != hipSuccess) {
      kA<<<dim3(256),dim3(512),0,stream>>>(q,b_hh,ws,h_full);
    }
  }
  kHw<<<1040,256,0,stream>>>(h_full, out_w, ws + WS_HW);
  kY<<<64,256,0,stream>>>(q, ws, bias, theta, y);
}